// Round 8
// baseline (263.502 us; speedup 1.0000x reference)
//
#include <hip/hip_runtime.h>
#include <math.h>

namespace {

constexpr int Bb   = 128;
constexpr int Ss   = 196;
constexpr int DIN  = 512;
constexpr int Hh   = 8;
constexpr int DKc  = 32;
constexpr int DVc  = 128;
constexpr int QKVD = 1536;   // H*(2*DK+DV)
constexpr int PIN  = 1024;   // H*DV
constexpr int Mrows = Bb * Ss; // 25088
constexpr float EPSc   = 1e-3f;
constexpr float SCALEc = 0.17677669529663687f; // 32^-0.5

typedef __bf16 bf16x8 __attribute__((ext_vector_type(8)));
typedef __bf16 bf16x4 __attribute__((ext_vector_type(4)));
typedef float  f32x4  __attribute__((ext_vector_type(4)));

// VT layout: [bh][quarter(4)][ 8192 elems ], quarter row stride 232 elems.
constexpr int VT_STRIDE = 232;                 // elems; 464 B = 16B-aligned, 2-way banks
constexpr size_t VT_QELEMS = 8192;             // padded quarter (32 rows x 232 = 7424 used)
constexpr size_t VT_BH = 4 * VT_QELEMS;        // 32768 elems per (b,h)

__device__ __forceinline__ void gl_lds16(const void* g, void* l) {
    __builtin_amdgcn_global_load_lds(
        (const __attribute__((address_space(1))) void*)g,
        (__attribute__((address_space(3))) void*)l, 16, 0, 0);
}

// ---------------- prep: both weight transposes + x f32->bf16, ONE launch ----------------
__global__ __launch_bounds__(256)
void prep(const float* __restrict__ W1, __bf16* __restrict__ WT1o,
          const float* __restrict__ W2, __bf16* __restrict__ WT2o,
          const float* __restrict__ x, __bf16* __restrict__ xb)
{
    int id = blockIdx.x;
    if (id >= 1280) {
        const int i = (id - 1280) * 256 + threadIdx.x;   // < Mrows*DIN/4 exactly
        float4 v = ((const float4*)x)[i];
        bf16x4 o = { (__bf16)v.x, (__bf16)v.y, (__bf16)v.z, (__bf16)v.w };
        ((bf16x4*)xb)[i] = o;
        return;
    }
    __shared__ float tile[32][33];
    const float* W; __bf16* WT; int K, N, bx, by;
    if (id < 768) { W = W1; WT = WT1o; K = 512;  N = 1536; bx = id % 48; by = id / 48; }
    else { id -= 768; W = W2; WT = WT2o; K = 1024; N = 512;  bx = id % 16; by = id / 16; }
    const int n0 = bx * 32, k0 = by * 32;
    const int tx = threadIdx.x & 31, ty = threadIdx.x >> 5;
#pragma unroll
    for (int i = ty; i < 32; i += 8)
        tile[i][tx] = W[(size_t)(k0 + i) * N + n0 + tx];
    __syncthreads();
#pragma unroll
    for (int i = ty; i < 32; i += 8)
        WT[(size_t)(n0 + i) * K + k0 + tx] = (__bf16)tile[tx][i];
}

// ---------------- GEMM1 v8: 3-deep ring pipeline (T3+T4+T5), 128x256 tile ----------------
// 512 thr (8 waves, 2M x 4N), wave-tile 64x64, BK=64, K=512 -> 8 phases.
// Ring of 3 x (A 16KB + B 32KB) = 144KB LDS. Phase p: stage tile p+2 (6 gl_lds,
// fire-and-forget), ds_read frags of tile p (XOR-swizzled), 32 MFMA (setprio),
// s_waitcnt vmcnt(6) [tile p+1 landed, p+2 in flight], raw s_barrier.
// vmcnt NEVER drains to 0 in steady state (T4) — the 2-phase barrier-drain stall
// that capped v5/v7 at ~620 TF is gone.
// LDS swizzle (rule #21, both-sides): physical = logical ^ ((byte>>7 & 7)<<4);
// gl_lds dest linear + inverse-swizzled GLOBAL source; ds_read applies the XOR.
// Epilogue: per-wave private 16KB scratch over the ring (after final barrier),
// QK waves -> full 128B-line stores to qkv; V waves -> 16B s-chunks to VTp.
__global__ __launch_bounds__(512)
void gemm1_bn_scatter(const __bf16* __restrict__ A, const __bf16* __restrict__ BT,
                      const float* __restrict__ bias, const float* __restrict__ gamma,
                      const float* __restrict__ beta, const float* __restrict__ mean,
                      const float* __restrict__ var,
                      __bf16* __restrict__ qkvO, __bf16* __restrict__ VTp)
{
    constexpr int K = DIN;               // 512
    __shared__ __align__(16) char sm[147456];   // 3 x 49152

    const int t    = threadIdx.x;
    const int wid  = t >> 6;             // 0..7
    const int lane = t & 63;
    const int lr   = lane & 15;
    const int q    = lane >> 4;

    constexpr int ntiles = 6;            // N/BN = 1536/256
    constexpr int nwg = 196 * ntiles;    // 1176, divisible by 8
    const int bid = (blockIdx.x & 7) * (nwg >> 3) + (blockIdx.x >> 3);
    const int m0 = (bid / ntiles) * 128;
    const int n0 = (bid % ntiles) * 256;
    const int wm  = (wid & 1) * 64;      // m-offset of wave tile
    const int wnL = (wid >> 1) * 64;     // n-offset of wave tile

    char* ring0 = sm;
    char* ring1 = sm + 49152;
    char* ring2 = sm + 98304;
    char* rings[3] = { ring0, ring1, ring2 };

    // stage one BK=64 K-tile (A[128][64] + B[256][64], both XOR-swizzled) : 6 gl_lds/thread
    auto STAGE = [&](int kt, char* rg) {
#pragma unroll
        for (int e = 0; e < 2; ++e) {            // A: 1024 chunks
            const int c = e * 512 + t;
            const int gsrc = (c & 7) ^ ((c >> 3) & 7);
            gl_lds16(A + (size_t)(m0 + (c >> 3)) * K + kt * 64 + gsrc * 8,
                     rg + c * 16);
        }
#pragma unroll
        for (int e = 0; e < 4; ++e) {            // B: 2048 chunks
            const int c = e * 512 + t;
            const int gsrc = (c & 7) ^ ((c >> 3) & 7);
            gl_lds16(BT + (size_t)(n0 + (c >> 3)) * K + kt * 64 + gsrc * 8,
                     rg + 16384 + c * 16);
        }
    };

    f32x4 acc[4][4] = {};

    // prologue: tiles 0,1 in flight; wait tile0 (vmcnt<=6), publish.
    STAGE(0, ring0);
    STAGE(1, ring1);
    asm volatile("s_waitcnt vmcnt(6)" ::: "memory");
    __builtin_amdgcn_s_barrier();
    __builtin_amdgcn_sched_barrier(0);

#pragma unroll
    for (int p = 0; p < 8; ++p) {
        if (p <= 5) STAGE(p + 2, rings[(p + 2) % 3]);
        const char* rg = rings[p % 3];

        bf16x8 aF[2][4], bF[2][4];
#pragma unroll
        for (int kh = 0; kh < 2; ++kh) {
#pragma unroll
            for (int i = 0; i < 4; ++i) {
                const int row = wm + i * 16 + lr;
                const int off = row * 128 + (((kh * 4 + q) ^ (row & 7)) << 4);
                aF[kh][i] = *(const bf16x8*)(rg + off);
            }
#pragma unroll
            for (int j = 0; j < 4; ++j) {
                const int row = wnL + j * 16 + lr;
                const int off = 16384 + row * 128 + (((kh * 4 + q) ^ (row & 7)) << 4);
                bF[kh][j] = *(const bf16x8*)(rg + off);
            }
        }
        __builtin_amdgcn_s_setprio(1);
#pragma unroll
        for (int kh = 0; kh < 2; ++kh)
#pragma unroll
            for (int i = 0; i < 4; ++i)
#pragma unroll
                for (int j = 0; j < 4; ++j)
                    acc[i][j] = __builtin_amdgcn_mfma_f32_16x16x32_bf16(
                        aF[kh][i], bF[kh][j], acc[i][j], 0, 0, 0);
        __builtin_amdgcn_s_setprio(0);

        if (p <= 5)      asm volatile("s_waitcnt vmcnt(6)" ::: "memory");
        else if (p == 6) asm volatile("s_waitcnt vmcnt(0)" ::: "memory");
        __builtin_amdgcn_s_barrier();            // publish tile p+1 / retire ring slot
        __builtin_amdgcn_sched_barrier(0);
    }
    // after the p=7 barrier: all waves done with the ring -> safe to reuse as scratch

    // ---- epilogue: wave-private scratch (16KB each), no barriers needed ----
    char* wsl = sm + wid * 16384;
    const int g64   = (n0 >> 6) + (wid >> 1);
    const bool isQK = (g64 % 3) == 0;
    const int h     = g64 / 3;
    const int nbase = n0 + (wid >> 1) * 64;
    const int mbase = m0 + (wid & 1) * 64;

    if (isQK) {
        __bf16* qk = (__bf16*)wsl;               // [64][72]
#pragma unroll
        for (int j = 0; j < 4; ++j) {
            const int n = nbase + j * 16 + lr;
            const float s  = gamma[n] * rsqrtf(var[n] + EPSc);
            const float tv = fmaf(bias[n] - mean[n], s, beta[n]);
#pragma unroll
            for (int i = 0; i < 4; ++i)
#pragma unroll
                for (int r = 0; r < 4; ++r)
                    qk[(i * 16 + q * 4 + r) * 72 + j * 16 + lr] =
                        (__bf16)fmaf(acc[i][j][r], s, tv);
        }
        // full 128B lines: 8 lanes x 16B per row; 8 rounds cover 64 rows
#pragma unroll
        for (int rr = 0; rr < 8; ++rr) {
            const int row = rr * 8 + (lane >> 3);
            const int g   = lane & 7;
            bf16x8 vv = *(const bf16x8*)(qk + row * 72 + g * 8);
            *(bf16x8*)(qkvO + (size_t)(mbase + row) * QKVD + nbase + g * 8) = vv;
        }
    } else {
        __bf16* vr = (__bf16*)wsl;               // [64 cols][72 rows] col-major
        const int d0 = nbase - h * 192 - 64;     // 0 or 64
#pragma unroll
        for (int j = 0; j < 4; ++j) {
            const int n = nbase + j * 16 + lr;
            const float s  = gamma[n] * rsqrtf(var[n] + EPSc);
            const float tv = fmaf(bias[n] - mean[n], s, beta[n]);
#pragma unroll
            for (int i = 0; i < 4; ++i) {
                bf16x4 pk = { (__bf16)fmaf(acc[i][j][0], s, tv),
                              (__bf16)fmaf(acc[i][j][1], s, tv),
                              (__bf16)fmaf(acc[i][j][2], s, tv),
                              (__bf16)fmaf(acc[i][j][3], s, tv) };
                *(bf16x4*)(vr + (j * 16 + lr) * 72 + i * 16 + q * 4) = pk;
            }
        }
        // 16B chunks along s: 512 chunks (64 cols x 8), 8 rounds
#pragma unroll
        for (int rr = 0; rr < 8; ++rr) {
            const int idx  = rr * 64 + lane;
            const int colL = idx >> 3;
            const int r0   = (idx & 7) * 8;
            const int d    = d0 + colL;
            const int mrow = mbase + r0;
            const int b_   = mrow / 196;
            const int s0   = mrow - b_ * 196;
            __bf16* dst0 = VTp + (size_t)(b_ * 8 + h) * VT_BH
                         + (size_t)(d >> 5) * VT_QELEMS + (size_t)(d & 31) * VT_STRIDE;
            bf16x8 vv = *(const bf16x8*)(vr + colL * 72 + r0);
            if (s0 <= 188) {
                *(bf16x8*)(dst0 + s0) = vv;
            } else {
#pragma unroll
                for (int e = 0; e < 8; ++e) {
                    int se = s0 + e;
                    __bf16* dst = dst0;
                    if (se >= 196) { se -= 196; dst += 8 * VT_BH; }
                    dst[se] = vv[e];
                }
            }
        }
    }
}

// ---------------- generic bf16 MFMA GEMM + BN (fp32 out) — GEMM2 ----------------
// v5 structure: double-buffered single-barrier K-loop.
template<int N, int K>
__global__ __launch_bounds__(256)
void gemm_bn_mfma(const __bf16* __restrict__ A, const __bf16* __restrict__ BT,
                  const float* __restrict__ bias, const float* __restrict__ gamma,
                  const float* __restrict__ beta, const float* __restrict__ mean,
                  const float* __restrict__ var, float* __restrict__ C)
{
    constexpr int BM = 128, BN = 128;
    __shared__ __align__(16) char sm[65536];
    const int t    = threadIdx.x;
    const int wave = t >> 6;
    const int lane = t & 63;
    const int lr   = lane & 15;
    const int q    = lane >> 4;
    constexpr int ntiles = N / BN;
    constexpr int nwg = 196 * ntiles;        // 784 for N=512 -> divisible by 8
    const int bid = (blockIdx.x & 7) * (nwg >> 3) + (blockIdx.x >> 3);
    const int m0 = (bid / ntiles) * BM;
    const int n0 = (bid % ntiles) * BN;
    const int wm = (wave & 1) * 64;
    const int wn = (wave >> 1) * 64;
    const __bf16* aG0 = A  + (size_t)(m0 + (t >> 2)) * K + (t & 3) * 8;
    const __bf16* aG1 = aG0 + (size_t)64 * K;
    const __bf16* bG0 = BT + (size_t)(n0 + (t >> 2)) * K + (t & 3) * 8;
    const __bf16* bG1 = bG0 + (size_t)64 * K;

    auto STAGE = [&](int k0, int cur) {
        char* lA = sm + cur * 16384 + wave * 1024;
        char* lB = sm + 32768 + cur * 16384 + wave * 1024;
        gl_lds16(aG0 + k0,      lA);
        gl_lds16(aG1 + k0,      lA + 4096);
        gl_lds16(aG0 + k0 + 32, lA + 8192);
        gl_lds16(aG1 + k0 + 32, lA + 8192 + 4096);
        gl_lds16(bG0 + k0,      lB);
        gl_lds16(bG1 + k0,      lB + 4096);
        gl_lds16(bG0 + k0 + 32, lB + 8192);
        gl_lds16(bG1 + k0 + 32, lB + 8192 + 4096);
    };

    f32x4 acc[4][4] = {};

    STAGE(0, 0);
    __syncthreads();
    int cur = 0;
    for (int k0 = 0; k0 < K; k0 += 64) {
        if (k0 + 64 < K) STAGE(k0 + 64, cur ^ 1);
        const __bf16* Abuf = (const __bf16*)(sm + cur * 16384);
        const __bf16* Bbuf = (const __bf16*)(sm + 32768 + cur * 16384);
#pragma unroll
        for (int kk = 0; kk < 2; ++kk) {
            bf16x8 aF[4], bF[4];
#pragma unroll
            for (int i = 0; i < 4; ++i)
                aF[i] = *(const bf16x8*)(Abuf + kk * 4096 + (wm + i * 16 + lr) * 32 + q * 8);
#pragma unroll
            for (int j = 0; j < 4; ++j)
                bF[j] = *(const bf16x8*)(Bbuf + kk * 4096 + (wn + j * 16 + lr) * 32 + q * 8);
#pragma unroll
            for (int i = 0; i < 4; ++i)
#pragma unroll
                for (int j = 0; j < 4; ++j)
                    acc[i][j] = __builtin_amdgcn_mfma_f32_16x16x32_bf16(
                        aF[i], bF[j], acc[i][j], 0, 0, 0);
        }
        __syncthreads();
        cur ^= 1;
    }
#pragma unroll
    for (int j = 0; j < 4; ++j) {
        const int n = n0 + wn + j * 16 + lr;
        const float s  = gamma[n] * rsqrtf(var[n] + EPSc);
        const float tv = fmaf(bias[n] - mean[n], s, beta[n]);
#pragma unroll
        for (int i = 0; i < 4; ++i) {
            const int mrow = m0 + wm + i * 16 + q * 4;
#pragma unroll
            for (int r = 0; r < 4; ++r)
                C[(size_t)(mrow + r) * N + n] = fmaf(acc[i][j][r], s, tv);
        }
    }
}

// ---------------- MFMA attention: one block per (b,h), 16 waves (v7) ----------------
__global__ __launch_bounds__(1024)
void attn_mfma(const __bf16* __restrict__ qkv, const __bf16* __restrict__ VTp,
               __bf16* __restrict__ hidden)
{
    __shared__ __align__(16) char smem[145920];
    __bf16* Kb = (__bf16*)smem;

    const int t = threadIdx.x;
    const int wave = t >> 6, lane = t & 63;
    const int lr = lane & 15, q = lane >> 4;
    const int bh = blockIdx.x;
    const int b = bh >> 3, h = bh & 7;
    const __bf16* qkvb = qkv + (size_t)b * 196 * QKVD + h * 192;

    // ---- issue V quarter 0 stage FIRST so HBM latency drains under K staging ----
    const char* gV = (const char*)(VTp + (size_t)bh * VT_BH);
    char* ldsV = smem + 113152;                 // 2 x 16384 double buffer
    gl_lds16(gV + wave * 1024 + lane * 16, ldsV + wave * 1024);

    // ---- stage K once: rows s=0..195, ch 32..63 -> Kb[s][40] ----
    if (t < 196 * 4) {
        const int s = t >> 2, c = t & 3;
        bf16x8 v = *(const bf16x8*)(qkvb + (size_t)s * QKVD + 32 + c * 8);
        *(bf16x8*)(Kb + s * 40 + c * 8) = v;
    }

    __syncthreads();                            // K ready; barrier drains vmcnt -> V0 ready

    const int qt = wave;                        // q-tile; valid rows only for qt<=12
    const bool wactive = (qt <= 12);
    __bf16* Pw = (__bf16*)(smem + 16640 + (wactive ? qt : 0) * 7424);   // [16][232]

    if (wactive) {
        // Q fragment straight from global
        int sQ = qt * 16 + lr; if (sQ > 195) sQ = 195;
        bf16x8 aQ = *(const bf16x8*)(qkv + ((size_t)b * 196 + sQ) * QKVD + h * 192 + q * 8);

        f32x4 sc[13];
#pragma unroll
        for (int nt = 0; nt < 13; ++nt) {
            bf16x8 bK = *(const bf16x8*)(Kb + (nt * 16 + lr) * 40 + q * 8);
            f32x4 z = {0.f, 0.f, 0.f, 0.f};
            sc[nt] = __builtin_amdgcn_mfma_f32_16x16x32_bf16(aQ, bK, z, 0, 0, 0);
        }
        // ---- register softmax over the 208 cols (cols>=196 masked) ----
        float mrow[4] = {-1e30f, -1e30f, -1e30f, -1e30f};
#pragma unroll
        for (int nt = 0; nt < 13; ++nt) {
            const bool valid = (nt < 12) | (lr < 4);
#pragma unroll
            for (int r = 0; r < 4; ++r) {
                float x = sc[nt][r] * SCALEc;
                sc[nt][r] = x;
                if (valid) mrow[r] = fmaxf(mrow[r], x);
            }
        }
#pragma unroll
        for (int d = 1; d < 16; d <<= 1)
#pragma unroll
            for (int r = 0; r < 4; ++r)
                mrow[r] = fmaxf(mrow[r], __shfl_xor(mrow[r], d, 64));
        float l[4] = {0.f, 0.f, 0.f, 0.f};
#pragma unroll
        for (int nt = 0; nt < 13; ++nt) {
            const bool valid = (nt < 12) | (lr < 4);
#pragma unroll
            for (int r = 0; r < 4; ++r) {
                float e = valid ? __expf(sc[nt][r] - mrow[r]) : 0.f;
                sc[nt][r] = e;
                l[r] += e;
            }
        }
#pragma unroll
        for (int d = 1; d < 16; d <<= 1)
#pragma unroll
            for (int r = 0; r < 4; ++r)
                l[r] += __shfl_xor(l[r], d, 64);
        float inv[4];
#pragma unroll
        for (int r = 0; r < 4; ++r) inv[r] = 1.f / l[r];

        // ---- P to LDS in A-operand layout: P[m=quad*4+r][col] (wave-private slot) ----
#pragma unroll
        for (int nt = 0; nt < 13; ++nt)
#pragma unroll
            for (int r = 0; r < 4; ++r)
                Pw[(q * 4 + r) * 232 + nt * 16 + lr] = (__bf16)(sc[nt][r] * inv[r]);
        // zero cols 208..231 (PV k-loop reads through col 223)
        for (int idx = lane; idx < 16 * 24; idx += 64) {
            int row = idx & 15, cz = 208 + (idx >> 4);
            Pw[row * 232 + cz] = (__bf16)0.f;
        }
    }
    // no barrier: P slots are wave-private (write->read ordered by lgkmcnt)

    // ---- PV over 4 dv-quarters; next quarter staged under current compute ----
    const int sbase = qt * 16 + q * 4;
    const bool sval = wactive && (sbase + 3 < 196);
    __bf16* hb = hidden + (size_t)b * 200704 + (size_t)h * 25088;

    for (int q4 = 0; q4 < 4; ++q4) {
        const __bf16* Vl = (const __bf16*)(ldsV + (q4 & 1) * 16384);
        if (q4 < 3)   // issue next quarter into the other buffer (drained by the barrier below)
            gl_lds16(gV + (size_t)(q4 + 1) * 16384 + wave * 1024 + lane * 16,
                     ldsV + ((q4 + 1) & 1) * 16384 + wave * 1024);
        if (wactive) {
            f32x4 o0 = {0.f, 0.f, 0.f, 0.f}, o1 = {0.f, 0.f, 0.f, 0.f};
#pragma unroll
            for (int kk = 0; kk < 7; ++kk) {
                bf16x8 aP = *(const bf16x8*)(Pw + lr * 232 + kk * 32 + q * 8);
                bf16x8 b0 = *(const bf16x8*)(Vl + lr * 232 + kk * 32 + q * 8);
                bf16x8 b1 = *(const bf16x8*)(Vl + (16 + lr) * 232 + kk * 32 + q * 8);
                o0 = __builtin_amdgcn_mfma_f32_16x16x32_bf16(aP, b0, o0, 0, 0, 0);
                o1 = __builtin_amdgcn_mfma_f32_16x16x32_bf16(aP, b1, o1, 0, 0, 0);
            }
            if (sval) {
#pragma unroll
                for (int nt2 = 0; nt2 < 2; ++nt2) {
                    f32x4 o = nt2 ? o1 : o0;
                    const int d = q4 * 32 + nt2 * 16 + lr;
                    bf16x4 pk;
#pragma unroll
                    for (int r = 0; r < 4; ++r) {
                        float x = o[r];
                        pk[r] = (__bf16)(x * fminf(fmaxf(x + 3.f, 0.f), 6.f) * (1.f / 6.f));
                    }
                    *(bf16x4*)(hb + (size_t)d * 196 + sbase) = pk;
                }
            }
        }
        if (q4 < 3) __syncthreads();
    }
}

} // namespace

extern "C" void kernel_launch(void* const* d_in, const int* in_sizes, int n_in,
                              void* d_out, int out_size, void* d_ws, size_t ws_size,
                              hipStream_t stream)
{
    const float* x    = (const float*)d_in[0];
    const float* Wqkv = (const float*)d_in[1];
    const float* bqkv = (const float*)d_in[2];
    const float* g1   = (const float*)d_in[3];
    const float* be1  = (const float*)d_in[4];
    const float* mu1  = (const float*)d_in[5];
    const float* va1  = (const float*)d_in[6];
    const float* Wp   = (const float*)d_in[7];
    const float* bp   = (const float*)d_in[8];
    const float* g2   = (const float*)d_in[9];
    const float* be2  = (const float*)d_in[10];
    const float* mu2  = (const float*)d_in[11];
    const float* va2  = (const float*)d_in[12];

    // workspace layout (bytes)
    char* ws = (char*)d_ws;
    __bf16* qkv    = (__bf16*)ws;                    // 25088*1536*2 = 77,070,336
    __bf16* VTp    = (__bf16*)(ws + 77070336);       // 1024*32768*2 = 67,108,864
    __bf16* hidden = (__bf16*)(ws + 144179200);      // 25088*1024*2 = 51,380,224
    __bf16* xb     = (__bf16*)(ws + 195559424);      // 25088*512*2  = 25,690,112
    __bf16* WT1    = (__bf16*)(ws + 221249536);      // 1536*512*2
    __bf16* WT2    = (__bf16*)(ws + 222822400);      // 512*1024*2
    float*  out    = (float*)d_out;

    // weight transposes + x cvt in one launch
    prep<<<dim3(13824), dim3(256), 0, stream>>>(Wqkv, WT1, Wp, WT2, x, xb);

    // GEMM1 + BN -> qkv bf16 (Q,K) + VTp (V pre-transposed); 8-phase ring pipeline
    gemm1_bn_scatter<<<dim3(196 * 6), dim3(512), 0, stream>>>(
        xb, WT1, bqkv, g1, be1, mu1, va1, qkv, VTp);

    // MFMA attention -> hidden bf16 (scrambled layout); 1 block per (b,h), 16 waves
    attn_mfma<<<dim3(Bb * Hh), dim3(1024), 0, stream>>>(qkv, VTp, hidden);

    // GEMM2 + BN -> out fp32
    gemm_bn_mfma<DIN, PIN><<<dim3(196 * (DIN / 128)), dim3(256), 0, stream>>>(
        hidden, WT2, bp, g2, be2, mu2, va2, out);
}